// Round 1
// baseline (228.475 us; speedup 1.0000x reference)
//
#include <hip/hip_runtime.h>

typedef float f4 __attribute__((ext_vector_type(4)));

#define TB 16  // batch rows per block

__device__ __forceinline__ float wred(float x) {
    #pragma unroll
    for (int m = 1; m < 64; m <<= 1) x += __shfl_xor(x, m);
    return x;
}

__global__ __launch_bounds__(256, 2) void scl_fused(
    const float* __restrict__ cond,   // [8192][64]
    const float* __restrict__ act,    // [8192][64]
    const float* __restrict__ W1,     // [64][256]
    const float* __restrict__ b1,     // [256]
    const float* __restrict__ W2,     // [256][256]
    const float* __restrict__ b2,     // [256]
    const float* __restrict__ W3,     // [256][512]
    const float* __restrict__ b3,     // [512]
    float* __restrict__ out)          // [8192][64]
{
    // 48KB LDS, overlaid:
    //   [0,4K)    cond tile [16][64]     (dead after layer1)
    //   [4K,20K)  x1 [16][256]           (dead after layer2)
    //   [0,32K)   H  [16][512]           (written in layer3, overlays cond+x1)
    //   [32K,48K) x2 [16][256]
    __shared__ char smem[49152];
    float* s_cond = (float*)smem;
    float* s_x1   = (float*)(smem + 4096);
    float* s_h    = (float*)smem;
    float* s_x2   = (float*)(smem + 32768);

    const int tid = threadIdx.x;
    const int rb  = blockIdx.x * TB;

    // stage cond tile: 16*64 floats = 256 float4, one per thread
    ((f4*)s_cond)[tid] = ((const f4*)(cond + rb * 64))[tid];
    __syncthreads();

    const int rq = tid >> 6;   // row quarter 0..3 (uniform within a wave)
    const int c4 = tid & 63;   // column group 0..63

    // ---------------- layer 1: [16x64] @ W1[64x256], tanh -> s_x1
    {
        float acc[4][4] = {};
        for (int k = 0; k < 64; k += 4) {
            f4 a[4];
            #pragma unroll
            for (int r = 0; r < 4; ++r)
                a[r] = *(const f4*)&s_cond[(4 * rq + r) * 64 + k];
            #pragma unroll
            for (int kk = 0; kk < 4; ++kk) {
                f4 w = *(const f4*)&W1[(k + kk) * 256 + 4 * c4];
                #pragma unroll
                for (int r = 0; r < 4; ++r)
                    #pragma unroll
                    for (int c = 0; c < 4; ++c)
                        acc[r][c] += a[r][kk] * w[c];
            }
        }
        f4 bb = *(const f4*)&b1[4 * c4];
        #pragma unroll
        for (int r = 0; r < 4; ++r) {
            f4 v;
            #pragma unroll
            for (int c = 0; c < 4; ++c) v[c] = tanhf(acc[r][c] + bb[c]);
            *(f4*)&s_x1[(4 * rq + r) * 256 + 4 * c4] = v;
        }
    }
    __syncthreads();

    // ---------------- layer 2: [16x256] @ W2[256x256], tanh -> s_x2
    {
        float acc[4][4] = {};
        for (int k = 0; k < 256; k += 4) {
            f4 a[4];
            #pragma unroll
            for (int r = 0; r < 4; ++r)
                a[r] = *(const f4*)&s_x1[(4 * rq + r) * 256 + k];
            #pragma unroll
            for (int kk = 0; kk < 4; ++kk) {
                f4 w = *(const f4*)&W2[(k + kk) * 256 + 4 * c4];
                #pragma unroll
                for (int r = 0; r < 4; ++r)
                    #pragma unroll
                    for (int c = 0; c < 4; ++c)
                        acc[r][c] += a[r][kk] * w[c];
            }
        }
        f4 bb = *(const f4*)&b2[4 * c4];
        #pragma unroll
        for (int r = 0; r < 4; ++r) {
            f4 v;
            #pragma unroll
            for (int c = 0; c < 4; ++c) v[c] = tanhf(acc[r][c] + bb[c]);
            *(f4*)&s_x2[(4 * rq + r) * 256 + 4 * c4] = v;
        }
    }
    __syncthreads();

    // ---------------- layer 3: [16x256] @ W3[256x512] + b3 -> s_h (overlays cond/x1)
    {
        float acc[4][8] = {};
        for (int k = 0; k < 256; k += 4) {
            f4 a[4];
            #pragma unroll
            for (int r = 0; r < 4; ++r)
                a[r] = *(const f4*)&s_x2[(4 * rq + r) * 256 + k];
            #pragma unroll
            for (int kk = 0; kk < 4; ++kk) {
                f4 w0 = *(const f4*)&W3[(k + kk) * 512 + 8 * c4];
                f4 w1 = *(const f4*)&W3[(k + kk) * 512 + 8 * c4 + 4];
                #pragma unroll
                for (int r = 0; r < 4; ++r) {
                    #pragma unroll
                    for (int c = 0; c < 4; ++c) {
                        acc[r][c]     += a[r][kk] * w0[c];
                        acc[r][c + 4] += a[r][kk] * w1[c];
                    }
                }
            }
        }
        f4 b30 = *(const f4*)&b3[8 * c4];
        f4 b31 = *(const f4*)&b3[8 * c4 + 4];
        #pragma unroll
        for (int r = 0; r < 4; ++r) {
            f4 v0, v1;
            #pragma unroll
            for (int c = 0; c < 4; ++c) {
                v0[c] = acc[r][c] + b30[c];
                v1[c] = acc[r][c + 4] + b31[c];
            }
            *(f4*)&s_h[(4 * rq + r) * 512 + 8 * c4]     = v0;
            *(f4*)&s_h[(4 * rq + r) * 512 + 8 * c4 + 4] = v1;
        }
    }
    __syncthreads();

    // ---------------- Householder: per row, apply 8 reflections to vectors.
    // scl = Q[:, :8] = R E, R = Q7 Q6 ... Q0 (each Qi symmetric).
    // a* = E^T R^T a  (apply c = 7..0 to a);  q = R (E a*)  (apply c = 0..7).
    const int wv = tid >> 6;
    const int ln = tid & 63;
    for (int rr = 0; rr < 4; ++rr) {
        const int r = wv * 4 + rr;
        f4 h0 = *(const f4*)&s_h[r * 512 + ln * 8];
        f4 h1 = *(const f4*)&s_h[r * 512 + ln * 8 + 4];
        float h[8] = {h0[0], h0[1], h0[2], h0[3], h1[0], h1[1], h1[2], h1[3]};
        float inv[8];
        #pragma unroll
        for (int c = 0; c < 8; ++c) {
            float s = wred(h[c] * h[c]);   // v.v
            inv[c] = 2.0f / s;
        }
        float u = act[(rb + r) * 64 + ln];
        #pragma unroll
        for (int c = 7; c >= 0; --c) {
            float d = wred(h[c] * u);
            u -= inv[c] * d * h[c];
        }
        float w = (ln < 8) ? u : 0.0f;
        #pragma unroll
        for (int c = 0; c < 8; ++c) {
            float d = wred(h[c] * w);
            w -= inv[c] * d * h[c];
        }
        out[(rb + r) * 64 + ln] = w;
    }
}

extern "C" void kernel_launch(void* const* d_in, const int* in_sizes, int n_in,
                              void* d_out, int out_size, void* d_ws, size_t ws_size,
                              hipStream_t stream) {
    const float* cond = (const float*)d_in[0];
    const float* act  = (const float*)d_in[1];
    const float* W1   = (const float*)d_in[2];
    const float* b1   = (const float*)d_in[3];
    const float* W2   = (const float*)d_in[4];
    const float* b2   = (const float*)d_in[5];
    const float* W3   = (const float*)d_in[6];
    const float* b3   = (const float*)d_in[7];
    float* outp = (float*)d_out;

    scl_fused<<<dim3(8192 / TB), dim3(256), 0, stream>>>(
        cond, act, W1, b1, W2, b2, W3, b3, outp);
}

// Round 2
// 77.885 us; speedup vs baseline: 2.9335x; 2.9335x over previous
//
#include <hip/hip_runtime.h>

typedef float f4 __attribute__((ext_vector_type(4)));

#define TB 16  // batch rows per block

__device__ __forceinline__ float wred(float x) {
    #pragma unroll
    for (int m = 1; m < 64; m <<= 1) x += __shfl_xor(x, m);
    return x;
}

__global__ __launch_bounds__(256, 2) void scl_fused(
    const float* __restrict__ cond,   // [8192][64]
    const float* __restrict__ act,    // [8192][64]
    const float* __restrict__ W1,     // [64][256]
    const float* __restrict__ b1,     // [256]
    const float* __restrict__ W2,     // [256][256]
    const float* __restrict__ b2,     // [256]
    const float* __restrict__ W3,     // [256][512]
    const float* __restrict__ b3,     // [512]
    float* __restrict__ out)          // [8192][64]
{
    // 48KB LDS, overlaid:
    //   [0,4K)    cond tile [16][64]     (dead after layer1)
    //   [4K,20K)  x1 [16][256]           (dead after layer2)
    //   [0,32K)   H  [16][512]           (written in layer3, overlays cond+x1)
    //   [32K,48K) x2 [16][256]
    __shared__ char smem[49152];
    float* s_cond = (float*)smem;
    float* s_x1   = (float*)(smem + 4096);
    float* s_h    = (float*)smem;
    float* s_x2   = (float*)(smem + 32768);

    const int tid = threadIdx.x;
    const int rb  = blockIdx.x * TB;

    // stage cond tile: 16*64 floats = 256 float4, one per thread
    ((f4*)s_cond)[tid] = ((const f4*)(cond + rb * 64))[tid];
    __syncthreads();

    const int rq = tid >> 6;   // row quarter 0..3 (uniform within a wave)
    const int c4 = tid & 63;   // column group 0..63

    // ---------------- layer 1: [16x64] @ W1[64x256], tanh -> s_x1
    {
        float acc[4][4] = {};
        #pragma unroll 2
        for (int k = 0; k < 64; k += 4) {
            f4 a[4];
            #pragma unroll
            for (int r = 0; r < 4; ++r)
                a[r] = *(const f4*)&s_cond[(4 * rq + r) * 64 + k];
            #pragma unroll
            for (int kk = 0; kk < 4; ++kk) {
                f4 w = *(const f4*)&W1[(k + kk) * 256 + 4 * c4];
                #pragma unroll
                for (int r = 0; r < 4; ++r)
                    #pragma unroll
                    for (int c = 0; c < 4; ++c)
                        acc[r][c] += a[r][kk] * w[c];
            }
        }
        f4 bb = *(const f4*)&b1[4 * c4];
        #pragma unroll
        for (int r = 0; r < 4; ++r) {
            f4 v;
            #pragma unroll
            for (int c = 0; c < 4; ++c) v[c] = tanhf(acc[r][c] + bb[c]);
            *(f4*)&s_x1[(4 * rq + r) * 256 + 4 * c4] = v;
        }
    }
    __syncthreads();

    // ---------------- layer 2: [16x256] @ W2[256x256], tanh -> s_x2
    {
        float acc[4][4] = {};
        #pragma unroll 2
        for (int k = 0; k < 256; k += 4) {
            f4 a[4];
            #pragma unroll
            for (int r = 0; r < 4; ++r)
                a[r] = *(const f4*)&s_x1[(4 * rq + r) * 256 + k];
            #pragma unroll
            for (int kk = 0; kk < 4; ++kk) {
                f4 w = *(const f4*)&W2[(k + kk) * 256 + 4 * c4];
                #pragma unroll
                for (int r = 0; r < 4; ++r)
                    #pragma unroll
                    for (int c = 0; c < 4; ++c)
                        acc[r][c] += a[r][kk] * w[c];
            }
        }
        f4 bb = *(const f4*)&b2[4 * c4];
        #pragma unroll
        for (int r = 0; r < 4; ++r) {
            f4 v;
            #pragma unroll
            for (int c = 0; c < 4; ++c) v[c] = tanhf(acc[r][c] + bb[c]);
            *(f4*)&s_x2[(4 * rq + r) * 256 + 4 * c4] = v;
        }
    }
    __syncthreads();

    // ---------------- layer 3: [16x256] @ W3[256x512] + b3 -> s_h (overlays cond/x1)
    {
        float acc[4][8] = {};
        #pragma unroll 2
        for (int k = 0; k < 256; k += 4) {
            f4 a[4];
            #pragma unroll
            for (int r = 0; r < 4; ++r)
                a[r] = *(const f4*)&s_x2[(4 * rq + r) * 256 + k];
            #pragma unroll
            for (int kk = 0; kk < 4; ++kk) {
                f4 w0 = *(const f4*)&W3[(k + kk) * 512 + 8 * c4];
                f4 w1 = *(const f4*)&W3[(k + kk) * 512 + 8 * c4 + 4];
                #pragma unroll
                for (int r = 0; r < 4; ++r) {
                    #pragma unroll
                    for (int c = 0; c < 4; ++c) {
                        acc[r][c]     += a[r][kk] * w0[c];
                        acc[r][c + 4] += a[r][kk] * w1[c];
                    }
                }
            }
        }
        f4 b30 = *(const f4*)&b3[8 * c4];
        f4 b31 = *(const f4*)&b3[8 * c4 + 4];
        #pragma unroll
        for (int r = 0; r < 4; ++r) {
            f4 v0, v1;
            #pragma unroll
            for (int c = 0; c < 4; ++c) {
                v0[c] = acc[r][c] + b30[c];
                v1[c] = acc[r][c + 4] + b31[c];
            }
            *(f4*)&s_h[(4 * rq + r) * 512 + 8 * c4]     = v0;
            *(f4*)&s_h[(4 * rq + r) * 512 + 8 * c4 + 4] = v1;
        }
    }
    __syncthreads();

    // ---------------- Householder: per row, apply 8 reflections to vectors.
    // scl = Q[:, :8] = R E, R = Q7 Q6 ... Q0 (each Qi symmetric).
    // a* = E^T R^T a  (apply c = 7..0 to a);  q = R (E a*)  (apply c = 0..7).
    const int wv = tid >> 6;
    const int ln = tid & 63;
    for (int rr = 0; rr < 4; ++rr) {
        const int r = wv * 4 + rr;
        f4 h0 = *(const f4*)&s_h[r * 512 + ln * 8];
        f4 h1 = *(const f4*)&s_h[r * 512 + ln * 8 + 4];
        float h[8] = {h0[0], h0[1], h0[2], h0[3], h1[0], h1[1], h1[2], h1[3]};
        float inv[8];
        #pragma unroll
        for (int c = 0; c < 8; ++c) {
            float s = wred(h[c] * h[c]);   // v.v
            inv[c] = 2.0f / s;
        }
        float u = act[(rb + r) * 64 + ln];
        #pragma unroll
        for (int c = 7; c >= 0; --c) {
            float d = wred(h[c] * u);
            u -= inv[c] * d * h[c];
        }
        float w = (ln < 8) ? u : 0.0f;
        #pragma unroll
        for (int c = 0; c < 8; ++c) {
            float d = wred(h[c] * w);
            w -= inv[c] * d * h[c];
        }
        out[(rb + r) * 64 + ln] = w;
    }
}

extern "C" void kernel_launch(void* const* d_in, const int* in_sizes, int n_in,
                              void* d_out, int out_size, void* d_ws, size_t ws_size,
                              hipStream_t stream) {
    const float* cond = (const float*)d_in[0];
    const float* act  = (const float*)d_in[1];
    const float* W1   = (const float*)d_in[2];
    const float* b1   = (const float*)d_in[3];
    const float* W2   = (const float*)d_in[4];
    const float* b2   = (const float*)d_in[5];
    const float* W3   = (const float*)d_in[6];
    const float* b3   = (const float*)d_in[7];
    float* outp = (float*)d_out;

    scl_fused<<<dim3(8192 / TB), dim3(256), 0, stream>>>(
        cond, act, W1, b1, W2, b2, W3, b3, outp);
}

// Round 3
// 76.358 us; speedup vs baseline: 2.9921x; 1.0200x over previous
//
#include <hip/hip_runtime.h>

typedef float f4 __attribute__((ext_vector_type(4)));

#define TB 16  // batch rows per block (4 per wave)

__device__ __forceinline__ float wred(float x) {
    #pragma unroll
    for (int m = 1; m < 64; m <<= 1) x += __shfl_xor(x, m);
    return x;
}

// tanh(x) = 1 - 2/(exp(2x)+1); exp via v_exp_f32. Handles +-inf limits correctly.
__device__ __forceinline__ float ftanh(float x) {
    float e = __expf(2.0f * x);
    return 1.0f - 2.0f / (e + 1.0f);
}

__global__ __launch_bounds__(256, 2) void scl_fused(
    const float* __restrict__ cond,   // [8192][64]
    const float* __restrict__ act,    // [8192][64]
    const float* __restrict__ W1,     // [64][256]
    const float* __restrict__ b1,     // [256]
    const float* __restrict__ W2,     // [256][256]
    const float* __restrict__ b2,     // [256]
    const float* __restrict__ W3,     // [256][512]
    const float* __restrict__ b3,     // [512]
    float* __restrict__ out)          // [8192][64]
{
    // Wave-PRIVATE 12KB arenas -> zero __syncthreads in the whole kernel.
    // Per-wave arena (floats):
    //   [0,256)      cond [4][64]   (dead after layer1)
    //   [256,1280)   x1   [4][256]  (dead after layer2)
    //   [0,2048)     h    [4][512]  (layer3 out; overlays cond+x1 of SAME wave)
    //   [2048,3072)  x2   [4][256]
    __shared__ char smem[49152];

    const int tid = threadIdx.x;
    const int rq  = tid >> 6;   // wave id 0..3
    const int ln  = tid & 63;   // lane
    const int rb  = blockIdx.x * TB;
    const int rw  = rb + 4 * rq;  // this wave's first global row

    float* base = (float*)(smem + rq * 12288);
    float* s_x1 = base + 256;
    float* s_x2 = base + 2048;

    // stage this wave's 4 cond rows (4*64 floats = 64 f4, one per lane)
    ((f4*)base)[ln] = ((const f4*)(cond + rw * 64))[ln];

    // ---------------- layer 1: [4x64] @ W1[64x256], tanh -> x1
    {
        float acc[4][4] = {};
        #pragma unroll 4
        for (int k = 0; k < 64; k += 4) {
            f4 a[4];
            #pragma unroll
            for (int r = 0; r < 4; ++r)
                a[r] = *(const f4*)&base[r * 64 + k];
            #pragma unroll
            for (int kk = 0; kk < 4; ++kk) {
                f4 w = *(const f4*)&W1[(k + kk) * 256 + 4 * ln];
                #pragma unroll
                for (int r = 0; r < 4; ++r)
                    #pragma unroll
                    for (int c = 0; c < 4; ++c)
                        acc[r][c] += a[r][kk] * w[c];
            }
        }
        f4 bb = *(const f4*)&b1[4 * ln];
        #pragma unroll
        for (int r = 0; r < 4; ++r) {
            f4 v;
            #pragma unroll
            for (int c = 0; c < 4; ++c) v[c] = ftanh(acc[r][c] + bb[c]);
            *(f4*)&s_x1[r * 256 + 4 * ln] = v;
        }
    }

    // ---------------- layer 2: [4x256] @ W2[256x256], tanh -> x2
    {
        float acc[4][4] = {};
        #pragma unroll 4
        for (int k = 0; k < 256; k += 4) {
            f4 a[4];
            #pragma unroll
            for (int r = 0; r < 4; ++r)
                a[r] = *(const f4*)&s_x1[r * 256 + k];
            #pragma unroll
            for (int kk = 0; kk < 4; ++kk) {
                f4 w = *(const f4*)&W2[(k + kk) * 256 + 4 * ln];
                #pragma unroll
                for (int r = 0; r < 4; ++r)
                    #pragma unroll
                    for (int c = 0; c < 4; ++c)
                        acc[r][c] += a[r][kk] * w[c];
            }
        }
        f4 bb = *(const f4*)&b2[4 * ln];
        #pragma unroll
        for (int r = 0; r < 4; ++r) {
            f4 v;
            #pragma unroll
            for (int c = 0; c < 4; ++c) v[c] = ftanh(acc[r][c] + bb[c]);
            *(f4*)&s_x2[r * 256 + 4 * ln] = v;
        }
    }

    // ---------------- layer 3: [4x256] @ W3[256x512] + b3 -> h (overlays cond/x1)
    {
        float acc[4][8] = {};
        #pragma unroll 2
        for (int k = 0; k < 256; k += 4) {
            f4 a[4];
            #pragma unroll
            for (int r = 0; r < 4; ++r)
                a[r] = *(const f4*)&s_x2[r * 256 + k];
            #pragma unroll
            for (int kk = 0; kk < 4; ++kk) {
                f4 w0 = *(const f4*)&W3[(k + kk) * 512 + 8 * ln];
                f4 w1 = *(const f4*)&W3[(k + kk) * 512 + 8 * ln + 4];
                #pragma unroll
                for (int r = 0; r < 4; ++r) {
                    #pragma unroll
                    for (int c = 0; c < 4; ++c) {
                        acc[r][c]     += a[r][kk] * w0[c];
                        acc[r][c + 4] += a[r][kk] * w1[c];
                    }
                }
            }
        }
        f4 b30 = *(const f4*)&b3[8 * ln];
        f4 b31 = *(const f4*)&b3[8 * ln + 4];
        #pragma unroll
        for (int r = 0; r < 4; ++r) {
            f4 v0, v1;
            #pragma unroll
            for (int c = 0; c < 4; ++c) {
                v0[c] = acc[r][c] + b30[c];
                v1[c] = acc[r][c + 4] + b31[c];
            }
            *(f4*)&base[r * 512 + 8 * ln]     = v0;
            *(f4*)&base[r * 512 + 8 * ln + 4] = v1;
        }
    }

    // ---------------- Householder: per row, apply 8 reflections to vectors.
    // scl = Q[:, :8] = R E, R = Q7 Q6 ... Q0 (each Qi symmetric).
    // a* = E^T R^T a  (apply c = 7..0 to a);  q = R (E a*)  (apply c = 0..7).
    #pragma unroll
    for (int rr = 0; rr < 4; ++rr) {
        f4 h0 = *(const f4*)&base[rr * 512 + ln * 8];
        f4 h1 = *(const f4*)&base[rr * 512 + ln * 8 + 4];
        float h[8] = {h0[0], h0[1], h0[2], h0[3], h1[0], h1[1], h1[2], h1[3]};
        float inv[8];
        #pragma unroll
        for (int c = 0; c < 8; ++c) {
            float s = wred(h[c] * h[c]);   // v.v
            inv[c] = 2.0f / s;
        }
        float u = act[(rw + rr) * 64 + ln];
        #pragma unroll
        for (int c = 7; c >= 0; --c) {
            float d = wred(h[c] * u);
            u -= inv[c] * d * h[c];
        }
        float w = (ln < 8) ? u : 0.0f;
        #pragma unroll
        for (int c = 0; c < 8; ++c) {
            float d = wred(h[c] * w);
            w -= inv[c] * d * h[c];
        }
        out[(rw + rr) * 64 + ln] = w;
    }
}

extern "C" void kernel_launch(void* const* d_in, const int* in_sizes, int n_in,
                              void* d_out, int out_size, void* d_ws, size_t ws_size,
                              hipStream_t stream) {
    const float* cond = (const float*)d_in[0];
    const float* act  = (const float*)d_in[1];
    const float* W1   = (const float*)d_in[2];
    const float* b1   = (const float*)d_in[3];
    const float* W2   = (const float*)d_in[4];
    const float* b2   = (const float*)d_in[5];
    const float* W3   = (const float*)d_in[6];
    const float* b3   = (const float*)d_in[7];
    float* outp = (float*)d_out;

    scl_fused<<<dim3(8192 / TB), dim3(256), 0, stream>>>(
        cond, act, W1, b1, W2, b2, W3, b3, outp);
}

// Round 4
// 43.221 us; speedup vs baseline: 5.2862x; 1.7667x over previous
//
#include <hip/hip_runtime.h>

typedef float f4 __attribute__((ext_vector_type(4)));
typedef float f32x4 __attribute__((ext_vector_type(4)));
typedef _Float16 f16x8 __attribute__((ext_vector_type(8)));

// XOR-swizzle for the h buffer: inject byte-addr bits 10:8 into bank bits 6:4.
#define HSWZ(o) ((o) ^ (((o) >> 4) & 0x70))

// ---------- pre-pass: W[K][N] fp32 -> MFMA B-fragment-ordered fp16 hi/lo ----------
// Fragment (nt,kt) for mfma_f32_16x16x32_f16: lane l holds B[32kt+8*(l>>4)+j][16nt+(l&15)], j=0..7.
// Storage per frag-pair p = nt*KT+kt: 1024 f16 = [hi: 64 lanes x 8][lo: 64 lanes x 8].
__global__ void prep_frags(const float* __restrict__ W, int K, int N,
                           _Float16* __restrict__ dst) {
    int t = blockIdx.x * 256 + threadIdx.x;
    int q = t & 3, l = (t >> 2) & 63, p = t >> 8;
    int KT = K >> 5;
    int kt = p % KT, nt = p / KT;
    int k = kt * 32 + ((l >> 4) << 3) + 2 * q;
    int n = nt * 16 + (l & 15);
    float w0 = W[k * N + n];
    float w1 = W[(k + 1) * N + n];
    _Float16 h0 = (_Float16)w0, h1 = (_Float16)w1;
    _Float16 l0 = (_Float16)(w0 - (float)h0), l1 = (_Float16)(w1 - (float)h1);
    int base = p * 1024 + l * 8 + 2 * q;
    dst[base]           = h0;
    dst[base + 1]       = h1;
    dst[base + 512]     = l0;
    dst[base + 512 + 1] = l1;
}

__device__ __forceinline__ float ftanh(float x) {
    float e = __expf(2.0f * x);
    return 1.0f - 2.0f / (e + 1.0f);
}
__device__ __forceinline__ float red16(float x) {  // sum over 16-lane groups
    x += __shfl_xor(x, 1); x += __shfl_xor(x, 2);
    x += __shfl_xor(x, 4); x += __shfl_xor(x, 8);
    return x;
}

// M=16 rows per block, 256 threads (4 waves). Split-fp16 MFMA for all 3 layers.
__global__ __launch_bounds__(256) void scl_mfma(
    const float* __restrict__ cond, const float* __restrict__ act,
    const float* __restrict__ b1, const float* __restrict__ b2,
    const float* __restrict__ b3,
    const _Float16* __restrict__ wf,   // frags: L1 @ 0, L2 @ 32768, L3 @ 163840 (f16 units)
    float* __restrict__ out)
{
    // LDS 50432 B:
    //   [0,16896)       x1 planes: hi[16][264] f16 @0, lo @8448   (dead after L2)
    //   [0,33536)       h  [16][524] f32, col-swizzled            (overlays x1, written in L3)
    //   [33536,50432)   x2 planes: hi @33536, lo @41984
    __shared__ char smem[50432];
    _Float16* x1h = (_Float16*)smem;
    _Float16* x1l = (_Float16*)(smem + 8448);
    float*    hbuf = (float*)smem;
    _Float16* x2h = (_Float16*)(smem + 33536);
    _Float16* x2l = (_Float16*)(smem + 41984);

    const int tid = threadIdx.x;
    const int w   = tid >> 6;   // wave 0..3
    const int l   = tid & 63;
    const int lr  = l & 15;     // A-row / C-col / B-col within tile
    const int lg  = l >> 4;     // k-group
    const int rb  = blockIdx.x * 16;

    const f16x8* wp = (const f16x8*)wf;   // 16B fragment rows

    // ---------------- layer 1: cond[16x64] @ W1[64x256] -> x1 planes
    {
        f16x8 ah[2], al[2];
        #pragma unroll
        for (int kt = 0; kt < 2; ++kt) {
            const float* src = cond + (rb + lr) * 64 + kt * 32 + lg * 8;
            f4 v0 = *(const f4*)src;
            f4 v1 = *(const f4*)(src + 4);
            float vv[8] = {v0[0], v0[1], v0[2], v0[3], v1[0], v1[1], v1[2], v1[3]};
            #pragma unroll
            for (int j = 0; j < 8; ++j) {
                _Float16 h = (_Float16)vv[j];
                ah[kt][j] = h;
                al[kt][j] = (_Float16)(vv[j] - (float)h);
            }
        }
        f32x4 acc[4] = {};
        #pragma unroll
        for (int ntL = 0; ntL < 4; ++ntL) {
            #pragma unroll
            for (int kt = 0; kt < 2; ++kt) {
                int pi = (w * 4 + ntL) * 2 + kt;
                f16x8 bh = wp[pi * 128 + l];
                f16x8 bl = wp[pi * 128 + 64 + l];
                acc[ntL] = __builtin_amdgcn_mfma_f32_16x16x32_f16(ah[kt], bh, acc[ntL], 0, 0, 0);
                acc[ntL] = __builtin_amdgcn_mfma_f32_16x16x32_f16(ah[kt], bl, acc[ntL], 0, 0, 0);
                acc[ntL] = __builtin_amdgcn_mfma_f32_16x16x32_f16(al[kt], bh, acc[ntL], 0, 0, 0);
            }
        }
        #pragma unroll
        for (int ntL = 0; ntL < 4; ++ntL) {
            int col = (w * 4 + ntL) * 16 + lr;
            float bb = b1[col];
            #pragma unroll
            for (int r = 0; r < 4; ++r) {
                float v = ftanh(acc[ntL][r] + bb);   // C/D: col=l&15, row=(l>>4)*4+r
                int row = lg * 4 + r;
                _Float16 h = (_Float16)v;
                x1h[row * 264 + col] = h;
                x1l[row * 264 + col] = (_Float16)(v - (float)h);
            }
        }
    }
    __syncthreads();

    // ---------------- layer 2: x1[16x256] @ W2[256x256] -> x2 planes
    {
        f32x4 acc[4] = {};
        #pragma unroll 2
        for (int kt = 0; kt < 8; ++kt) {
            int cb = kt * 32 + lg * 8;
            f16x8 ah = *(const f16x8*)&x1h[lr * 264 + cb];
            f16x8 al = *(const f16x8*)&x1l[lr * 264 + cb];
            #pragma unroll
            for (int ntL = 0; ntL < 4; ++ntL) {
                int pi = (w * 4 + ntL) * 8 + kt;
                f16x8 bh = wp[4096 + pi * 128 + l];
                f16x8 bl = wp[4096 + pi * 128 + 64 + l];
                acc[ntL] = __builtin_amdgcn_mfma_f32_16x16x32_f16(ah, bh, acc[ntL], 0, 0, 0);
                acc[ntL] = __builtin_amdgcn_mfma_f32_16x16x32_f16(ah, bl, acc[ntL], 0, 0, 0);
                acc[ntL] = __builtin_amdgcn_mfma_f32_16x16x32_f16(al, bh, acc[ntL], 0, 0, 0);
            }
        }
        __syncthreads();   // x1 reads done block-wide before anything else; x2 writes next
        #pragma unroll
        for (int ntL = 0; ntL < 4; ++ntL) {
            int col = (w * 4 + ntL) * 16 + lr;
            float bb = b2[col];
            #pragma unroll
            for (int r = 0; r < 4; ++r) {
                float v = ftanh(acc[ntL][r] + bb);
                int row = lg * 4 + r;
                _Float16 h = (_Float16)v;
                x2h[row * 264 + col] = h;
                x2l[row * 264 + col] = (_Float16)(v - (float)h);
            }
        }
    }
    __syncthreads();

    // ---------------- layer 3: x2[16x256] @ W3[256x512] + b3 -> hbuf (f32, swizzled; overlays x1)
    {
        f32x4 acc[8] = {};
        #pragma unroll 2
        for (int kt = 0; kt < 8; ++kt) {
            int cb = kt * 32 + lg * 8;
            f16x8 ah = *(const f16x8*)&x2h[lr * 264 + cb];
            f16x8 al = *(const f16x8*)&x2l[lr * 264 + cb];
            #pragma unroll
            for (int ntL = 0; ntL < 8; ++ntL) {
                int pi = (w * 8 + ntL) * 8 + kt;
                f16x8 bh = wp[20480 + pi * 128 + l];
                f16x8 bl = wp[20480 + pi * 128 + 64 + l];
                acc[ntL] = __builtin_amdgcn_mfma_f32_16x16x32_f16(ah, bh, acc[ntL], 0, 0, 0);
                acc[ntL] = __builtin_amdgcn_mfma_f32_16x16x32_f16(ah, bl, acc[ntL], 0, 0, 0);
                acc[ntL] = __builtin_amdgcn_mfma_f32_16x16x32_f16(al, bh, acc[ntL], 0, 0, 0);
            }
        }
        #pragma unroll
        for (int ntL = 0; ntL < 8; ++ntL) {
            int col = (w * 8 + ntL) * 16 + lr;
            float bb = b3[col];
            #pragma unroll
            for (int r = 0; r < 4; ++r) {
                int row = lg * 4 + r;
                hbuf[row * 524 + (HSWZ(col * 4) >> 2)] = acc[ntL][r] + bb;
            }
        }
    }
    __syncthreads();

    // ---------------- Householder: 4 rows/wave, 16 lanes/row, 4 n's per lane.
    // Lane (w, lg=r, lr=c) owns h[hrow][32c .. 32c+32) = {h_cc[n], n = 4c+j, cc = 0..7}.
    {
        const int r = lg, c = lr;
        const int hrow = w * 4 + r;
        const int grow = rb + hrow;
        f4 hv[8];
        #pragma unroll
        for (int s = 0; s < 8; ++s) {
            int bo = HSWZ(c * 128 + s * 16);
            hv[s] = *(const f4*)&hbuf[hrow * 524 + (bo >> 2)];
        }
        float h[8][4];
        #pragma unroll
        for (int cc = 0; cc < 8; ++cc)
            #pragma unroll
            for (int j = 0; j < 4; ++j) {
                int e = 8 * j + cc;
                h[cc][j] = hv[e >> 2][e & 3];
            }
        float inv[8];
        #pragma unroll
        for (int cc = 0; cc < 8; ++cc) {
            float s = h[cc][0]*h[cc][0] + h[cc][1]*h[cc][1]
                    + h[cc][2]*h[cc][2] + h[cc][3]*h[cc][3];
            inv[cc] = 2.0f / red16(s);
        }
        f4 av = *(const f4*)&act[grow * 64 + c * 4];
        float u[4] = {av[0], av[1], av[2], av[3]};
        #pragma unroll
        for (int cc = 7; cc >= 0; --cc) {           // a* = E^T Q0..Q7 a
            float d = red16(h[cc][0]*u[0] + h[cc][1]*u[1] + h[cc][2]*u[2] + h[cc][3]*u[3]);
            float t = inv[cc] * d;
            #pragma unroll
            for (int j = 0; j < 4; ++j) u[j] -= t * h[cc][j];
        }
        float wv[4];
        #pragma unroll
        for (int j = 0; j < 4; ++j) wv[j] = (c < 2) ? u[j] : 0.0f;  // E a*
        #pragma unroll
        for (int cc = 0; cc < 8; ++cc) {            // q = Q7..Q0 (E a*)
            float d = red16(h[cc][0]*wv[0] + h[cc][1]*wv[1] + h[cc][2]*wv[2] + h[cc][3]*wv[3]);
            float t = inv[cc] * d;
            #pragma unroll
            for (int j = 0; j < 4; ++j) wv[j] -= t * h[cc][j];
        }
        f4 o = {wv[0], wv[1], wv[2], wv[3]};
        *(f4*)&out[grow * 64 + c * 4] = o;
    }
}

extern "C" void kernel_launch(void* const* d_in, const int* in_sizes, int n_in,
                              void* d_out, int out_size, void* d_ws, size_t ws_size,
                              hipStream_t stream) {
    const float* cond = (const float*)d_in[0];
    const float* act  = (const float*)d_in[1];
    const float* W1   = (const float*)d_in[2];
    const float* b1   = (const float*)d_in[3];
    const float* W2   = (const float*)d_in[4];
    const float* b2   = (const float*)d_in[5];
    const float* W3   = (const float*)d_in[6];
    const float* b3   = (const float*)d_in[7];
    float* outp = (float*)d_out;

    // d_ws: fp16 fragment store, 851968 bytes total.
    _Float16* wf = (_Float16*)d_ws;
    prep_frags<<<dim3(32),  dim3(256), 0, stream>>>(W1, 64,  256, wf);
    prep_frags<<<dim3(128), dim3(256), 0, stream>>>(W2, 256, 256, wf + 32768);
    prep_frags<<<dim3(256), dim3(256), 0, stream>>>(W3, 256, 512, wf + 163840);

    scl_mfma<<<dim3(512), dim3(256), 0, stream>>>(cond, act, b1, b2, b3, wf, outp);
}

// Round 5
// 30.641 us; speedup vs baseline: 7.4566x; 1.4106x over previous
//
#include <hip/hip_runtime.h>

typedef float f4 __attribute__((ext_vector_type(4)));
typedef float f32x4 __attribute__((ext_vector_type(4)));
typedef _Float16 f16x8 __attribute__((ext_vector_type(8)));

// XOR-swizzle for the h buffer: inject byte-addr bits 10:8 into bank bits 6:4.
#define HSWZ(o) ((o) ^ (((o) >> 4) & 0x70))

// ---------- pre-pass (fused): W[K][N] fp32 -> MFMA B-fragment-ordered fp16 hi/lo ----------
// Fragment (nt,kt) for mfma_f32_16x16x32_f16: lane l holds B[32kt+8*(l>>4)+j][16nt+(l&15)], j=0..7.
// Page p = nt*KT+kt: 1024 f16 = [hi: 64 lanes x 8][lo: 64 lanes x 8].
// Regions (f16 units): W1 @ 0 (32 pages), W2 @ 32768 (128 pages), W3 @ 163840 (256 pages).
__global__ void prep_frags_all(const float* __restrict__ W1,
                               const float* __restrict__ W2,
                               const float* __restrict__ W3,
                               _Float16* __restrict__ dst) {
    int p = blockIdx.x;                 // one page per block (256 threads)
    int q = threadIdx.x & 3, l = (threadIdx.x >> 2) & 63;
    const float* W; int K, N, lp; size_t off;
    if (p < 32)       { W = W1; K = 64;  N = 256; lp = p;       off = 0; }
    else if (p < 160) { W = W2; K = 256; N = 256; lp = p - 32;  off = 32768; }
    else              { W = W3; K = 256; N = 512; lp = p - 160; off = 163840; }
    int KT = K >> 5;
    int kt = lp % KT, nt = lp / KT;
    int k = kt * 32 + ((l >> 4) << 3) + 2 * q;
    int n = nt * 16 + (l & 15);
    float w0 = W[k * N + n];
    float w1 = W[(k + 1) * N + n];
    _Float16 h0 = (_Float16)w0, h1 = (_Float16)w1;
    _Float16 l0 = (_Float16)(w0 - (float)h0), l1 = (_Float16)(w1 - (float)h1);
    size_t base = off + (size_t)lp * 1024 + l * 8 + 2 * q;
    dst[base]           = h0;
    dst[base + 1]       = h1;
    dst[base + 512]     = l0;
    dst[base + 512 + 1] = l1;
}

__device__ __forceinline__ float ftanh(float x) {
    float e = __expf(2.0f * x);
    return 1.0f - 2.0f / (e + 1.0f);
}
__device__ __forceinline__ float red16(float x) {  // sum over 16-lane groups
    x += __shfl_xor(x, 1); x += __shfl_xor(x, 2);
    x += __shfl_xor(x, 4); x += __shfl_xor(x, 8);
    return x;
}

// M=32 rows per block, 512 threads (8 waves). Each wave owns a column slice and
// BOTH 16-row A-tiles -> every B-fragment load feeds 2 MFMAs (weight traffic halved).
__global__ __launch_bounds__(512, 2) void scl_mfma(
    const float* __restrict__ cond, const float* __restrict__ act,
    const float* __restrict__ b1, const float* __restrict__ b2,
    const float* __restrict__ b3,
    const _Float16* __restrict__ wf,
    float* __restrict__ out)
{
    // LDS 100864 B:
    //   [0,16896)        x1 hi [32][264] f16   (dead after L2)
    //   [16896,33792)    x1 lo                 (dead after L2)
    //   [0,67072)        h [32][524] f32, col-swizzled (overlays x1, written in L3)
    //   [67072,83968)    x2 hi [32][264]
    //   [83968,100864)   x2 lo
    __shared__ char smem[100864];
    _Float16* x1h = (_Float16*)smem;
    _Float16* x1l = (_Float16*)(smem + 16896);
    float*    hbuf = (float*)smem;
    _Float16* x2h = (_Float16*)(smem + 67072);
    _Float16* x2l = (_Float16*)(smem + 83968);

    const int tid = threadIdx.x;
    const int w   = tid >> 6;   // wave 0..7
    const int l   = tid & 63;
    const int lr  = l & 15;     // A-row / C-col / B-col within tile
    const int lg  = l >> 4;     // k-group
    const int rb  = blockIdx.x * 32;

    const f16x8* wp = (const f16x8*)wf;   // 16B fragment rows

    // ---------------- layer 1: cond[32x64] @ W1[64x256] -> x1 planes
    {
        f16x8 ah[2][2], al[2][2];   // [mrow][kt]
        #pragma unroll
        for (int m = 0; m < 2; ++m)
            #pragma unroll
            for (int kt = 0; kt < 2; ++kt) {
                const float* src = cond + (rb + m * 16 + lr) * 64 + kt * 32 + lg * 8;
                f4 v0 = *(const f4*)src;
                f4 v1 = *(const f4*)(src + 4);
                float vv[8] = {v0[0], v0[1], v0[2], v0[3], v1[0], v1[1], v1[2], v1[3]};
                #pragma unroll
                for (int j = 0; j < 8; ++j) {
                    _Float16 h = (_Float16)vv[j];
                    ah[m][kt][j] = h;
                    al[m][kt][j] = (_Float16)(vv[j] - (float)h);
                }
            }
        f32x4 acc[2][2] = {};
        #pragma unroll
        for (int ntL = 0; ntL < 2; ++ntL) {
            #pragma unroll
            for (int kt = 0; kt < 2; ++kt) {
                int pi = (w * 2 + ntL) * 2 + kt;
                f16x8 bh = wp[pi * 128 + l];
                f16x8 bl = wp[pi * 128 + 64 + l];
                #pragma unroll
                for (int m = 0; m < 2; ++m) {
                    acc[m][ntL] = __builtin_amdgcn_mfma_f32_16x16x32_f16(ah[m][kt], bh, acc[m][ntL], 0, 0, 0);
                    acc[m][ntL] = __builtin_amdgcn_mfma_f32_16x16x32_f16(ah[m][kt], bl, acc[m][ntL], 0, 0, 0);
                    acc[m][ntL] = __builtin_amdgcn_mfma_f32_16x16x32_f16(al[m][kt], bh, acc[m][ntL], 0, 0, 0);
                }
            }
        }
        #pragma unroll
        for (int ntL = 0; ntL < 2; ++ntL) {
            int col = (w * 2 + ntL) * 16 + lr;
            float bb = b1[col];
            #pragma unroll
            for (int m = 0; m < 2; ++m)
                #pragma unroll
                for (int r = 0; r < 4; ++r) {
                    float v = ftanh(acc[m][ntL][r] + bb);   // C/D: col=l&15, row=(l>>4)*4+r
                    int row = m * 16 + lg * 4 + r;
                    _Float16 h = (_Float16)v;
                    x1h[row * 264 + col] = h;
                    x1l[row * 264 + col] = (_Float16)(v - (float)h);
                }
        }
    }
    __syncthreads();

    // ---------------- layer 2: x1[32x256] @ W2[256x256] -> x2 planes
    {
        f32x4 acc[2][2] = {};
        #pragma unroll 2
        for (int kt = 0; kt < 8; ++kt) {
            int cb = kt * 32 + lg * 8;
            f16x8 ah0 = *(const f16x8*)&x1h[lr * 264 + cb];
            f16x8 al0 = *(const f16x8*)&x1l[lr * 264 + cb];
            f16x8 ah1 = *(const f16x8*)&x1h[(16 + lr) * 264 + cb];
            f16x8 al1 = *(const f16x8*)&x1l[(16 + lr) * 264 + cb];
            #pragma unroll
            for (int ntL = 0; ntL < 2; ++ntL) {
                int pi = (w * 2 + ntL) * 8 + kt;
                f16x8 bh = wp[4096 + pi * 128 + l];
                f16x8 bl = wp[4096 + pi * 128 + 64 + l];
                acc[0][ntL] = __builtin_amdgcn_mfma_f32_16x16x32_f16(ah0, bh, acc[0][ntL], 0, 0, 0);
                acc[0][ntL] = __builtin_amdgcn_mfma_f32_16x16x32_f16(ah0, bl, acc[0][ntL], 0, 0, 0);
                acc[0][ntL] = __builtin_amdgcn_mfma_f32_16x16x32_f16(al0, bh, acc[0][ntL], 0, 0, 0);
                acc[1][ntL] = __builtin_amdgcn_mfma_f32_16x16x32_f16(ah1, bh, acc[1][ntL], 0, 0, 0);
                acc[1][ntL] = __builtin_amdgcn_mfma_f32_16x16x32_f16(ah1, bl, acc[1][ntL], 0, 0, 0);
                acc[1][ntL] = __builtin_amdgcn_mfma_f32_16x16x32_f16(al1, bh, acc[1][ntL], 0, 0, 0);
            }
        }
        #pragma unroll
        for (int ntL = 0; ntL < 2; ++ntL) {
            int col = (w * 2 + ntL) * 16 + lr;
            float bb = b2[col];
            #pragma unroll
            for (int m = 0; m < 2; ++m)
                #pragma unroll
                for (int r = 0; r < 4; ++r) {
                    float v = ftanh(acc[m][ntL][r] + bb);
                    int row = m * 16 + lg * 4 + r;
                    _Float16 h = (_Float16)v;
                    x2h[row * 264 + col] = h;
                    x2l[row * 264 + col] = (_Float16)(v - (float)h);
                }
        }
    }
    __syncthreads();

    // ---------------- layer 3: x2[32x256] @ W3[256x512] + b3 -> hbuf (f32, swizzled; overlays x1)
    {
        f32x4 acc[2][4] = {};
        #pragma unroll 2
        for (int kt = 0; kt < 8; ++kt) {
            int cb = kt * 32 + lg * 8;
            f16x8 ah0 = *(const f16x8*)&x2h[lr * 264 + cb];
            f16x8 al0 = *(const f16x8*)&x2l[lr * 264 + cb];
            f16x8 ah1 = *(const f16x8*)&x2h[(16 + lr) * 264 + cb];
            f16x8 al1 = *(const f16x8*)&x2l[(16 + lr) * 264 + cb];
            #pragma unroll
            for (int ntL = 0; ntL < 4; ++ntL) {
                int pi = (w * 4 + ntL) * 8 + kt;
                f16x8 bh = wp[20480 + pi * 128 + l];
                f16x8 bl = wp[20480 + pi * 128 + 64 + l];
                acc[0][ntL] = __builtin_amdgcn_mfma_f32_16x16x32_f16(ah0, bh, acc[0][ntL], 0, 0, 0);
                acc[0][ntL] = __builtin_amdgcn_mfma_f32_16x16x32_f16(ah0, bl, acc[0][ntL], 0, 0, 0);
                acc[0][ntL] = __builtin_amdgcn_mfma_f32_16x16x32_f16(al0, bh, acc[0][ntL], 0, 0, 0);
                acc[1][ntL] = __builtin_amdgcn_mfma_f32_16x16x32_f16(ah1, bh, acc[1][ntL], 0, 0, 0);
                acc[1][ntL] = __builtin_amdgcn_mfma_f32_16x16x32_f16(ah1, bl, acc[1][ntL], 0, 0, 0);
                acc[1][ntL] = __builtin_amdgcn_mfma_f32_16x16x32_f16(al1, bh, acc[1][ntL], 0, 0, 0);
            }
        }
        #pragma unroll
        for (int ntL = 0; ntL < 4; ++ntL) {
            int col = (w * 4 + ntL) * 16 + lr;
            float bb = b3[col];
            #pragma unroll
            for (int m = 0; m < 2; ++m)
                #pragma unroll
                for (int r = 0; r < 4; ++r) {
                    int row = m * 16 + lg * 4 + r;
                    hbuf[row * 524 + (HSWZ(col * 4) >> 2)] = acc[m][ntL][r] + bb;
                }
        }
    }
    __syncthreads();

    // ---------------- Householder: 4 rows/wave, 16 lanes/row, 4 n's per lane.
    // Lane (w, lg=r, lr=c) owns h[hrow][32c .. 32c+32) = {h_cc[n], n = 4c+j, cc = 0..7}.
    {
        const int c = lr;
        const int hrow = w * 4 + lg;
        const int grow = rb + hrow;
        f4 hv[8];
        #pragma unroll
        for (int s = 0; s < 8; ++s) {
            int bo = HSWZ(c * 128 + s * 16);
            hv[s] = *(const f4*)&hbuf[hrow * 524 + (bo >> 2)];
        }
        float h[8][4];
        #pragma unroll
        for (int cc = 0; cc < 8; ++cc)
            #pragma unroll
            for (int j = 0; j < 4; ++j) {
                int e = 8 * j + cc;
                h[cc][j] = hv[e >> 2][e & 3];
            }
        float inv[8];
        #pragma unroll
        for (int cc = 0; cc < 8; ++cc) {
            float s = h[cc][0]*h[cc][0] + h[cc][1]*h[cc][1]
                    + h[cc][2]*h[cc][2] + h[cc][3]*h[cc][3];
            inv[cc] = 2.0f / red16(s);
        }
        f4 av = *(const f4*)&act[grow * 64 + c * 4];
        float u[4] = {av[0], av[1], av[2], av[3]};
        #pragma unroll
        for (int cc = 7; cc >= 0; --cc) {           // a* = E^T Q0..Q7 a
            float d = red16(h[cc][0]*u[0] + h[cc][1]*u[1] + h[cc][2]*u[2] + h[cc][3]*u[3]);
            float t = inv[cc] * d;
            #pragma unroll
            for (int j = 0; j < 4; ++j) u[j] -= t * h[cc][j];
        }
        float wv[4];
        #pragma unroll
        for (int j = 0; j < 4; ++j) wv[j] = (c < 2) ? u[j] : 0.0f;  // E a*
        #pragma unroll
        for (int cc = 0; cc < 8; ++cc) {            // q = Q7..Q0 (E a*)
            float d = red16(h[cc][0]*wv[0] + h[cc][1]*wv[1] + h[cc][2]*wv[2] + h[cc][3]*wv[3]);
            float t = inv[cc] * d;
            #pragma unroll
            for (int j = 0; j < 4; ++j) wv[j] -= t * h[cc][j];
        }
        f4 o = {wv[0], wv[1], wv[2], wv[3]};
        *(f4*)&out[grow * 64 + c * 4] = o;
    }
}

extern "C" void kernel_launch(void* const* d_in, const int* in_sizes, int n_in,
                              void* d_out, int out_size, void* d_ws, size_t ws_size,
                              hipStream_t stream) {
    const float* cond = (const float*)d_in[0];
    const float* act  = (const float*)d_in[1];
    const float* W1   = (const float*)d_in[2];
    const float* b1   = (const float*)d_in[3];
    const float* W2   = (const float*)d_in[4];
    const float* b2   = (const float*)d_in[5];
    const float* W3   = (const float*)d_in[6];
    const float* b3   = (const float*)d_in[7];
    float* outp = (float*)d_out;

    // d_ws: fp16 fragment store, 851968 bytes total.
    _Float16* wf = (_Float16*)d_ws;
    prep_frags_all<<<dim3(416), dim3(256), 0, stream>>>(W1, W2, W3, wf);
    scl_mfma<<<dim3(256), dim3(512), 0, stream>>>(cond, act, b1, b2, b3, wf, outp);
}

// Round 6
// 28.339 us; speedup vs baseline: 8.0622x; 1.0812x over previous
//
#include <hip/hip_runtime.h>

typedef float f4 __attribute__((ext_vector_type(4)));
typedef float f2 __attribute__((ext_vector_type(2)));
typedef float f32x4 __attribute__((ext_vector_type(4)));
typedef _Float16 f16x8 __attribute__((ext_vector_type(8)));

// Swizzle for the h16 buffer: XOR byte-addr bits 9:7 into bank bits 6:4
// (16B-chunk-preserving, bijective within a 1024B row).
#define HSWZ16(o) ((o) ^ (((o) >> 3) & 0x70))

// ---------- pre-pass (fused): W[K][N] fp32 -> MFMA B-fragment-ordered fp16 (single plane) ----------
// Fragment (nt,kt) for mfma_f32_16x16x32_f16: lane l holds B[32kt+8*(l>>4)+j][16nt+(l&15)], j=0..7.
// Page p = nt*KT+kt: 512 f16 = 64 lanes x 8.
// Regions (f16 units): W1 @ 0 (32 pages), W2 @ 16384 (128 pages), W3 @ 81920 (256 pages).
__global__ void prep_frags_all(const float* __restrict__ W1,
                               const float* __restrict__ W2,
                               const float* __restrict__ W3,
                               _Float16* __restrict__ dst) {
    int p = blockIdx.x;                 // one page per 256-thread block
    int q = threadIdx.x & 3, l = (threadIdx.x >> 2) & 63;
    const float* W; int K, N, lp; size_t off;
    if (p < 32)       { W = W1; K = 64;  N = 256; lp = p;       off = 0; }
    else if (p < 160) { W = W2; K = 256; N = 256; lp = p - 32;  off = 16384; }
    else              { W = W3; K = 256; N = 512; lp = p - 160; off = 81920; }
    int KT = K >> 5;
    int kt = lp % KT, nt = lp / KT;
    int k = kt * 32 + ((l >> 4) << 3) + 2 * q;
    int n = nt * 16 + (l & 15);
    size_t base = off + (size_t)lp * 512 + l * 8 + 2 * q;
    dst[base]     = (_Float16)W[k * N + n];
    dst[base + 1] = (_Float16)W[(k + 1) * N + n];
}

__device__ __forceinline__ float ftanh(float x) {
    float e = __expf(2.0f * x);
    return 1.0f - 2.0f / (e + 1.0f);
}
__device__ __forceinline__ float red32(float x) {  // sum over 32-lane groups
    x += __shfl_xor(x, 1); x += __shfl_xor(x, 2);  x += __shfl_xor(x, 4);
    x += __shfl_xor(x, 8); x += __shfl_xor(x, 16);
    return x;
}

// M=16 rows/block, 512 threads (8 waves), 512 blocks. 2-term split:
// acc += ah*bh; acc += al*bh  (weights fp16, activations double-fp16).
__global__ __launch_bounds__(512, 4) void scl_mfma(
    const float* __restrict__ cond, const float* __restrict__ act,
    const float* __restrict__ b1, const float* __restrict__ b2,
    const float* __restrict__ b3,
    const _Float16* __restrict__ wf,
    float* __restrict__ out)
{
    // LDS 33792 B:
    //   [0,8448)        x1 hi [16][264] f16   (dead after L2)
    //   [8448,16896)    x1 lo                 (dead after L2)
    //   [0,16768)       h16 [16][524] f16, swizzled (overlays x1, written in L3)
    //   [16896,25344)   x2 hi
    //   [25344,33792)   x2 lo
    __shared__ char smem[33792];
    _Float16* x1h = (_Float16*)smem;
    _Float16* x1l = (_Float16*)(smem + 8448);
    _Float16* x2h = (_Float16*)(smem + 16896);
    _Float16* x2l = (_Float16*)(smem + 25344);

    const int tid = threadIdx.x;
    const int w   = tid >> 6;   // wave 0..7
    const int l   = tid & 63;
    const int lr  = l & 15;     // A-row / C-col / B-col within tile
    const int lg  = l >> 4;     // k-group
    const int rb  = blockIdx.x * 16;

    const f16x8* wp = (const f16x8*)wf;   // 16B fragment rows; page stride = 64

    // ---------------- layer 1: cond[16x64] @ W1[64x256] -> x1 planes
    {
        f16x8 ah[2], al[2];   // [kt]
        #pragma unroll
        for (int kt = 0; kt < 2; ++kt) {
            const float* src = cond + (rb + lr) * 64 + kt * 32 + lg * 8;
            f4 v0 = *(const f4*)src;
            f4 v1 = *(const f4*)(src + 4);
            float vv[8] = {v0[0], v0[1], v0[2], v0[3], v1[0], v1[1], v1[2], v1[3]};
            #pragma unroll
            for (int j = 0; j < 8; ++j) {
                _Float16 hx = (_Float16)vv[j];
                ah[kt][j] = hx;
                al[kt][j] = (_Float16)(vv[j] - (float)hx);
            }
        }
        f32x4 acc[2] = {};
        #pragma unroll
        for (int ntL = 0; ntL < 2; ++ntL) {
            #pragma unroll
            for (int kt = 0; kt < 2; ++kt) {
                int pi = (w * 2 + ntL) * 2 + kt;
                f16x8 bh = wp[pi * 64 + l];
                acc[ntL] = __builtin_amdgcn_mfma_f32_16x16x32_f16(ah[kt], bh, acc[ntL], 0, 0, 0);
                acc[ntL] = __builtin_amdgcn_mfma_f32_16x16x32_f16(al[kt], bh, acc[ntL], 0, 0, 0);
            }
        }
        #pragma unroll
        for (int ntL = 0; ntL < 2; ++ntL) {
            int col = (w * 2 + ntL) * 16 + lr;
            float bb = b1[col];
            #pragma unroll
            for (int r = 0; r < 4; ++r) {
                float v = ftanh(acc[ntL][r] + bb);   // C/D: col=l&15, row=(l>>4)*4+r
                int row = lg * 4 + r;
                _Float16 hx = (_Float16)v;
                x1h[row * 264 + col] = hx;
                x1l[row * 264 + col] = (_Float16)(v - (float)hx);
            }
        }
    }
    __syncthreads();

    // ---------------- layer 2: x1[16x256] @ W2[256x256] -> x2 planes
    {
        f32x4 acc[2] = {};
        #pragma unroll 2
        for (int kt = 0; kt < 8; ++kt) {
            int cb = kt * 32 + lg * 8;
            f16x8 ah = *(const f16x8*)&x1h[lr * 264 + cb];
            f16x8 al = *(const f16x8*)&x1l[lr * 264 + cb];
            #pragma unroll
            for (int ntL = 0; ntL < 2; ++ntL) {
                int pi = (w * 2 + ntL) * 8 + kt;
                f16x8 bh = wp[2048 + pi * 64 + l];
                acc[ntL] = __builtin_amdgcn_mfma_f32_16x16x32_f16(ah, bh, acc[ntL], 0, 0, 0);
                acc[ntL] = __builtin_amdgcn_mfma_f32_16x16x32_f16(al, bh, acc[ntL], 0, 0, 0);
            }
        }
        #pragma unroll
        for (int ntL = 0; ntL < 2; ++ntL) {
            int col = (w * 2 + ntL) * 16 + lr;
            float bb = b2[col];
            #pragma unroll
            for (int r = 0; r < 4; ++r) {
                float v = ftanh(acc[ntL][r] + bb);
                int row = lg * 4 + r;
                _Float16 hx = (_Float16)v;
                x2h[row * 264 + col] = hx;
                x2l[row * 264 + col] = (_Float16)(v - (float)hx);
            }
        }
    }
    __syncthreads();

    // ---------------- layer 3: x2[16x256] @ W3[256x512] + b3 -> h16 (swizzled; overlays x1)
    {
        f32x4 acc[4] = {};
        #pragma unroll 2
        for (int kt = 0; kt < 8; ++kt) {
            int cb = kt * 32 + lg * 8;
            f16x8 ah = *(const f16x8*)&x2h[lr * 264 + cb];
            f16x8 al = *(const f16x8*)&x2l[lr * 264 + cb];
            #pragma unroll
            for (int ntL = 0; ntL < 4; ++ntL) {
                int pi = (w * 4 + ntL) * 8 + kt;
                f16x8 bh = wp[10240 + pi * 64 + l];
                acc[ntL] = __builtin_amdgcn_mfma_f32_16x16x32_f16(ah, bh, acc[ntL], 0, 0, 0);
                acc[ntL] = __builtin_amdgcn_mfma_f32_16x16x32_f16(al, bh, acc[ntL], 0, 0, 0);
            }
        }
        #pragma unroll
        for (int ntL = 0; ntL < 4; ++ntL) {
            int col = (w * 4 + ntL) * 16 + lr;
            float bb = b3[col];
            #pragma unroll
            for (int r = 0; r < 4; ++r) {
                int row = lg * 4 + r;
                *(_Float16*)(smem + row * 1048 + HSWZ16(col * 2)) = (_Float16)(acc[ntL][r] + bb);
            }
        }
    }
    __syncthreads();

    // ---------------- Householder: 2 rows/wave, 32 lanes/row, 2 n's per lane.
    // Lane (w, rh, c) owns n in {2c, 2c+1}; h element e = 8n+cc at byte 2e (swizzled).
    {
        const int c  = l & 31;
        const int rh = l >> 5;
        const int hrow = w * 2 + rh;
        const int grow = rb + hrow;
        f16x8 hv[2];
        #pragma unroll
        for (int j = 0; j < 2; ++j)
            hv[j] = *(const f16x8*)(smem + hrow * 1048 + HSWZ16(c * 32 + j * 16));
        float h[8][2];
        #pragma unroll
        for (int cc = 0; cc < 8; ++cc) {
            h[cc][0] = (float)hv[0][cc];
            h[cc][1] = (float)hv[1][cc];
        }
        float inv[8];
        #pragma unroll
        for (int cc = 0; cc < 8; ++cc) {
            float s = h[cc][0] * h[cc][0] + h[cc][1] * h[cc][1];
            inv[cc] = 2.0f / red32(s);
        }
        f2 av = *(const f2*)&act[grow * 64 + 2 * c];
        float u[2] = {av[0], av[1]};
        #pragma unroll
        for (int cc = 7; cc >= 0; --cc) {           // a* = E^T Q0..Q7 a
            float d = red32(h[cc][0] * u[0] + h[cc][1] * u[1]);
            float t = inv[cc] * d;
            u[0] -= t * h[cc][0];
            u[1] -= t * h[cc][1];
        }
        float wv[2];
        wv[0] = (c < 4) ? u[0] : 0.0f;               // E a*  (n = 2c, 2c+1 < 8)
        wv[1] = (c < 4) ? u[1] : 0.0f;
        #pragma unroll
        for (int cc = 0; cc < 8; ++cc) {            // q = Q7..Q0 (E a*)
            float d = red32(h[cc][0] * wv[0] + h[cc][1] * wv[1]);
            float t = inv[cc] * d;
            wv[0] -= t * h[cc][0];
            wv[1] -= t * h[cc][1];
        }
        f2 o = {wv[0], wv[1]};
        *(f2*)&out[grow * 64 + 2 * c] = o;
    }
}

extern "C" void kernel_launch(void* const* d_in, const int* in_sizes, int n_in,
                              void* d_out, int out_size, void* d_ws, size_t ws_size,
                              hipStream_t stream) {
    const float* cond = (const float*)d_in[0];
    const float* act  = (const float*)d_in[1];
    const float* W1   = (const float*)d_in[2];
    const float* b1   = (const float*)d_in[3];
    const float* W2   = (const float*)d_in[4];
    const float* b2   = (const float*)d_in[5];
    const float* W3   = (const float*)d_in[6];
    const float* b3   = (const float*)d_in[7];
    float* outp = (float*)d_out;

    // d_ws: fp16 fragment store, 425984 bytes.
    _Float16* wf = (_Float16*)d_ws;
    prep_frags_all<<<dim3(416), dim3(256), 0, stream>>>(W1, W2, W3, wf);
    scl_mfma<<<dim3(512), dim3(512), 0, stream>>>(cond, act, b1, b2, b3, wf, outp);
}

// Round 7
// 26.607 us; speedup vs baseline: 8.5872x; 1.0651x over previous
//
#include <hip/hip_runtime.h>

typedef float f4 __attribute__((ext_vector_type(4)));
typedef float f2 __attribute__((ext_vector_type(2)));
typedef float f32x4 __attribute__((ext_vector_type(4)));
typedef _Float16 f16x8 __attribute__((ext_vector_type(8)));

// Swizzle for the h16 buffer: XOR byte-addr bits 9:7 into bank bits 6:4
// (16B-chunk-preserving, bijective within a 1024B row).
#define HSWZ16(o) ((o) ^ (((o) >> 3) & 0x70))

// Barrier that drains LDS ops only — outstanding GLOBAL loads survive,
// so cross-phase weight prefetch stays in flight (avoids the vmcnt(0)
// full drain hipcc emits for __syncthreads).
#define BARLG() asm volatile("s_waitcnt lgkmcnt(0)\n\ts_barrier" ::: "memory")

// ---------- pre-pass: W -> MFMA B-fragment-ordered fp16, fully coalesced ----------
// Page p = nt*KT+kt: 512 f16, lane l holds B[32kt+8*(l>>4)+j][16nt+(l&15)], j=0..7.
// Regions (f16 units): W1 @ 0 (32 pages), W2 @ 16384 (128), W3 @ 81920 (256).
// One block per 32k x 256n strip: stage coalesced -> LDS, transpose-read, store pages.
__global__ __launch_bounds__(256) void prep_frags_all(
    const float* __restrict__ W1, const float* __restrict__ W2,
    const float* __restrict__ W3, _Float16* __restrict__ dst) {
    __shared__ float s[32 * 264];
    const int b = blockIdx.x, tid = threadIdx.x;
    const float* W; int N, kt, nh, KT; size_t off;
    if (b < 2)       { W = W1; N = 256; KT = 2; kt = b;            nh = 0;          off = 0; }
    else if (b < 10) { W = W2; N = 256; KT = 8; kt = b - 2;        nh = 0;          off = 16384; }
    else             { W = W3; N = 512; KT = 8; kt = (b - 10) >> 1; nh = (b - 10) & 1; off = 81920; }
    #pragma unroll
    for (int rep = 0; rep < 8; ++rep) {
        int fi = rep * 256 + tid;
        int row = fi >> 6, c4 = fi & 63;                     // 64 f4 per 256-col row
        f4 v = *(const f4*)&W[(kt * 32 + row) * N + nh * 256 + c4 * 4];
        *(f4*)&s[row * 264 + c4 * 4] = v;
    }
    __syncthreads();
    const int wv = tid >> 6, l = tid & 63, lr = l & 15, lg = l >> 4;
    #pragma unroll
    for (int p = 0; p < 4; ++p) {
        int lnt = wv * 4 + p;                                // local nt 0..15
        f16x8 o;
        #pragma unroll
        for (int j = 0; j < 8; ++j)
            o[j] = (_Float16)s[(lg * 8 + j) * 264 + lnt * 16 + lr];
        int page = (nh * 16 + lnt) * KT + kt;
        *(f16x8*)&dst[off + (size_t)page * 512 + l * 8] = o; // coalesced 1KB/wave
    }
}

__device__ __forceinline__ float ftanh(float x) {
    float e = __expf(2.0f * x);
    return 1.0f - 2.0f / (e + 1.0f);
}
__device__ __forceinline__ float red32(float x) {  // sum over 32-lane groups
    x += __shfl_xor(x, 1); x += __shfl_xor(x, 2);  x += __shfl_xor(x, 4);
    x += __shfl_xor(x, 8); x += __shfl_xor(x, 16);
    return x;
}

// M=16 rows/block, 512 threads (8 waves), 512 blocks. 2-term split fp16 MFMA.
// Weight fragments for phase k+1 are issued during phase k and kept in flight
// across lgkm-only barriers.
__global__ __launch_bounds__(512, 4) void scl_mfma(
    const float* __restrict__ cond, const float* __restrict__ act,
    const float* __restrict__ b1, const float* __restrict__ b2,
    const float* __restrict__ b3,
    const _Float16* __restrict__ wf,
    float* __restrict__ out)
{
    // LDS 33792 B:
    //   [0,8448)      x1 hi [16][264] f16   (dead after L2)
    //   [8448,16896)  x1 lo                 (dead after L2)
    //   [0,16896)     h16 [16] rows, stride 1056 B, swizzled (overlays x1, written in L3)
    //   [16896,25344) x2 hi
    //   [25344,33792) x2 lo
    __shared__ char smem[33792];
    _Float16* x1h = (_Float16*)smem;
    _Float16* x1l = (_Float16*)(smem + 8448);
    _Float16* x2h = (_Float16*)(smem + 16896);
    _Float16* x2l = (_Float16*)(smem + 25344);

    const int tid = threadIdx.x;
    const int w   = tid >> 6;   // wave 0..7
    const int l   = tid & 63;
    const int lr  = l & 15;
    const int lg  = l >> 4;
    const int rb  = blockIdx.x * 16;
    const f16x8* wp = (const f16x8*)wf;   // page stride 64 (f16x8 units)

    // ---- early issue: act (for HH tail), cond, biases, W1 frags, ALL W2 frags
    const int hrow = w * 2 + (l >> 5), hc = l & 31;
    f2 av = *(const f2*)&act[(rb + hrow) * 64 + 2 * hc];
    const float* crow = cond + (rb + lr) * 64 + lg * 8;
    f4 c0a = *(const f4*)crow;
    f4 c0b = *(const f4*)(crow + 4);
    f4 c1a = *(const f4*)(crow + 32);
    f4 c1b = *(const f4*)(crow + 36);
    f16x8 w1f[2][2];
    #pragma unroll
    for (int n = 0; n < 2; ++n)
        #pragma unroll
        for (int kt = 0; kt < 2; ++kt)
            w1f[n][kt] = wp[((w * 2 + n) * 2 + kt) * 64 + l];
    f16x8 w2f[2][8];
    #pragma unroll
    for (int n = 0; n < 2; ++n)
        #pragma unroll
        for (int kt = 0; kt < 8; ++kt)
            w2f[n][kt] = wp[2048 + ((w * 2 + n) * 8 + kt) * 64 + l];
    float b1v[2], b2v[2], b3v[4];
    #pragma unroll
    for (int n = 0; n < 2; ++n) {
        b1v[n] = b1[(w * 2 + n) * 16 + lr];
        b2v[n] = b2[(w * 2 + n) * 16 + lr];
    }
    #pragma unroll
    for (int n = 0; n < 4; ++n) b3v[n] = b3[(w * 4 + n) * 16 + lr];

    // ---------------- layer 1: cond[16x64] @ W1 -> x1 planes
    {
        float v0[8] = {c0a[0], c0a[1], c0a[2], c0a[3], c0b[0], c0b[1], c0b[2], c0b[3]};
        float v1[8] = {c1a[0], c1a[1], c1a[2], c1a[3], c1b[0], c1b[1], c1b[2], c1b[3]};
        f16x8 ah[2], al[2];
        #pragma unroll
        for (int j = 0; j < 8; ++j) {
            _Float16 h0 = (_Float16)v0[j];
            ah[0][j] = h0; al[0][j] = (_Float16)(v0[j] - (float)h0);
            _Float16 h1 = (_Float16)v1[j];
            ah[1][j] = h1; al[1][j] = (_Float16)(v1[j] - (float)h1);
        }
        f32x4 acc[2] = {};
        #pragma unroll
        for (int n = 0; n < 2; ++n)
            #pragma unroll
            for (int kt = 0; kt < 2; ++kt) {
                acc[n] = __builtin_amdgcn_mfma_f32_16x16x32_f16(ah[kt], w1f[n][kt], acc[n], 0, 0, 0);
                acc[n] = __builtin_amdgcn_mfma_f32_16x16x32_f16(al[kt], w1f[n][kt], acc[n], 0, 0, 0);
            }
        #pragma unroll
        for (int n = 0; n < 2; ++n) {
            int col = (w * 2 + n) * 16 + lr;
            #pragma unroll
            for (int r = 0; r < 4; ++r) {
                float v = ftanh(acc[n][r] + b1v[n]);   // C/D: col=l&15, row=(l>>4)*4+r
                int row = lg * 4 + r;
                _Float16 hx = (_Float16)v;
                x1h[row * 264 + col] = hx;
                x1l[row * 264 + col] = (_Float16)(v - (float)hx);
            }
        }
    }
    BARLG();

    // ---------------- layer 2: x1 @ W2 -> x2 planes  (W3 first half prefetched here)
    f16x8 w3f[4][8];
    #pragma unroll
    for (int n = 0; n < 4; ++n)
        #pragma unroll
        for (int kt = 0; kt < 4; ++kt)
            w3f[n][kt] = wp[10240 + ((w * 4 + n) * 8 + kt) * 64 + l];
    {
        f32x4 acc[2] = {};
        #pragma unroll
        for (int kt = 0; kt < 8; ++kt) {
            int cb = kt * 32 + lg * 8;
            f16x8 ah = *(const f16x8*)&x1h[lr * 264 + cb];
            f16x8 al = *(const f16x8*)&x1l[lr * 264 + cb];
            #pragma unroll
            for (int n = 0; n < 2; ++n) {
                acc[n] = __builtin_amdgcn_mfma_f32_16x16x32_f16(ah, w2f[n][kt], acc[n], 0, 0, 0);
                acc[n] = __builtin_amdgcn_mfma_f32_16x16x32_f16(al, w2f[n][kt], acc[n], 0, 0, 0);
            }
        }
        #pragma unroll
        for (int n = 0; n < 2; ++n) {
            int col = (w * 2 + n) * 16 + lr;
            #pragma unroll
            for (int r = 0; r < 4; ++r) {
                float v = ftanh(acc[n][r] + b2v[n]);
                int row = lg * 4 + r;
                _Float16 hx = (_Float16)v;
                x2h[row * 264 + col] = hx;
                x2l[row * 264 + col] = (_Float16)(v - (float)hx);
            }
        }
    }
    BARLG();

    // ---------------- layer 3: x2 @ W3 + b3 -> h16 (swizzled; overlays x1)
    #pragma unroll
    for (int n = 0; n < 4; ++n)
        #pragma unroll
        for (int kt = 4; kt < 8; ++kt)
            w3f[n][kt] = wp[10240 + ((w * 4 + n) * 8 + kt) * 64 + l];
    {
        f32x4 acc[4] = {};
        #pragma unroll
        for (int kt = 0; kt < 8; ++kt) {
            int cb = kt * 32 + lg * 8;
            f16x8 ah = *(const f16x8*)&x2h[lr * 264 + cb];
            f16x8 al = *(const f16x8*)&x2l[lr * 264 + cb];
            #pragma unroll
            for (int n = 0; n < 4; ++n) {
                acc[n] = __builtin_amdgcn_mfma_f32_16x16x32_f16(ah, w3f[n][kt], acc[n], 0, 0, 0);
                acc[n] = __builtin_amdgcn_mfma_f32_16x16x32_f16(al, w3f[n][kt], acc[n], 0, 0, 0);
            }
        }
        #pragma unroll
        for (int n = 0; n < 4; ++n) {
            int col = (w * 4 + n) * 16 + lr;
            #pragma unroll
            for (int r = 0; r < 4; ++r) {
                int row = lg * 4 + r;
                *(_Float16*)(smem + row * 1056 + HSWZ16(col * 2)) = (_Float16)(acc[n][r] + b3v[n]);
            }
        }
    }
    BARLG();

    // ---------------- Householder: 2 rows/wave, 32 lanes/row, 2 n's per lane.
    {
        f16x8 hv[2];
        #pragma unroll
        for (int j = 0; j < 2; ++j)
            hv[j] = *(const f16x8*)(smem + hrow * 1056 + HSWZ16(hc * 32 + j * 16));
        float h[8][2];
        #pragma unroll
        for (int cc = 0; cc < 8; ++cc) {
            h[cc][0] = (float)hv[0][cc];
            h[cc][1] = (float)hv[1][cc];
        }
        float inv[8];
        #pragma unroll
        for (int cc = 0; cc < 8; ++cc) {
            float s = h[cc][0] * h[cc][0] + h[cc][1] * h[cc][1];
            inv[cc] = 2.0f / red32(s);
        }
        float u[2] = {av[0], av[1]};
        #pragma unroll
        for (int cc = 7; cc >= 0; --cc) {           // a* = E^T Q0..Q7 a
            float d = red32(h[cc][0] * u[0] + h[cc][1] * u[1]);
            float t = inv[cc] * d;
            u[0] -= t * h[cc][0];
            u[1] -= t * h[cc][1];
        }
        float wv[2];
        wv[0] = (hc < 4) ? u[0] : 0.0f;              // E a*
        wv[1] = (hc < 4) ? u[1] : 0.0f;
        #pragma unroll
        for (int cc = 0; cc < 8; ++cc) {            // q = Q7..Q0 (E a*)
            float d = red32(h[cc][0] * wv[0] + h[cc][1] * wv[1]);
            float t = inv[cc] * d;
            wv[0] -= t * h[cc][0];
            wv[1] -= t * h[cc][1];
        }
        f2 o = {wv[0], wv[1]};
        *(f2*)&out[(rb + hrow) * 64 + 2 * hc] = o;
    }
}

extern "C" void kernel_launch(void* const* d_in, const int* in_sizes, int n_in,
                              void* d_out, int out_size, void* d_ws, size_t ws_size,
                              hipStream_t stream) {
    const float* cond = (const float*)d_in[0];
    const float* act  = (const float*)d_in[1];
    const float* W1   = (const float*)d_in[2];
    const float* b1   = (const float*)d_in[3];
    const float* W2   = (const float*)d_in[4];
    const float* b2   = (const float*)d_in[5];
    const float* W3   = (const float*)d_in[6];
    const float* b3   = (const float*)d_in[7];
    float* outp = (float*)d_out;

    _Float16* wf = (_Float16*)d_ws;   // 425984 bytes
    prep_frags_all<<<dim3(26), dim3(256), 0, stream>>>(W1, W2, W3, wf);
    scl_mfma<<<dim3(512), dim3(512), 0, stream>>>(cond, act, b1, b2, b3, wf, outp);
}

// Round 8
// 26.384 us; speedup vs baseline: 8.6595x; 1.0084x over previous
//
#include <hip/hip_runtime.h>

typedef float f4 __attribute__((ext_vector_type(4)));
typedef float f32x4 __attribute__((ext_vector_type(4)));
typedef _Float16 f16x8 __attribute__((ext_vector_type(8)));

// Swizzle for the h16 buffer: XOR byte-addr bits 9:7 into bank bits 6:4
// (16B-chunk-preserving, bijective within a 1024B row).
#define HSWZ16(o) ((o) ^ (((o) >> 3) & 0x70))

// Barrier draining LDS ops only — outstanding GLOBAL loads stay in flight.
#define BARLG() asm volatile("s_waitcnt lgkmcnt(0)\n\ts_barrier" ::: "memory")

// ---------- pre-pass: W -> MFMA B-fragment-ordered fp16, fully coalesced ----------
// Page p = nt*KT+kt: 512 f16, lane l holds B[32kt+8*(l>>4)+j][16nt+(l&15)], j=0..7.
// Regions (f16 units): W1 @ 0 (32 pages), W2 @ 16384 (128), W3 @ 81920 (256).
__global__ __launch_bounds__(256) void prep_frags_all(
    const float* __restrict__ W1, const float* __restrict__ W2,
    const float* __restrict__ W3, _Float16* __restrict__ dst) {
    __shared__ float s[32 * 264];
    const int b = blockIdx.x, tid = threadIdx.x;
    const float* W; int N, kt, nh, KT; size_t off;
    if (b < 2)       { W = W1; N = 256; KT = 2; kt = b;            nh = 0;          off = 0; }
    else if (b < 10) { W = W2; N = 256; KT = 8; kt = b - 2;        nh = 0;          off = 16384; }
    else             { W = W3; N = 512; KT = 8; kt = (b - 10) >> 1; nh = (b - 10) & 1; off = 81920; }
    #pragma unroll
    for (int rep = 0; rep < 8; ++rep) {
        int fi = rep * 256 + tid;
        int row = fi >> 6, c4 = fi & 63;
        f4 v = *(const f4*)&W[(kt * 32 + row) * N + nh * 256 + c4 * 4];
        *(f4*)&s[row * 264 + c4 * 4] = v;
    }
    __syncthreads();
    const int wv = tid >> 6, l = tid & 63, lr = l & 15, lg = l >> 4;
    #pragma unroll
    for (int p = 0; p < 4; ++p) {
        int lnt = wv * 4 + p;
        f16x8 o;
        #pragma unroll
        for (int j = 0; j < 8; ++j)
            o[j] = (_Float16)s[(lg * 8 + j) * 264 + lnt * 16 + lr];
        int page = (nh * 16 + lnt) * KT + kt;
        *(f16x8*)&dst[off + (size_t)page * 512 + l * 8] = o;
    }
}

__device__ __forceinline__ float ftanh(float x) {
    float e = __expf(2.0f * x);
    return 1.0f - 2.0f / (e + 1.0f);
}
__device__ __forceinline__ float red8(float x) {   // sum over aligned 8-lane groups
    x += __shfl_xor(x, 1); x += __shfl_xor(x, 2); x += __shfl_xor(x, 4);
    return x;
}

// M=32 rows/block, 1024 threads (16 waves), 256 blocks = 1 block/CU.
// Single fp16 plane for activations (x error ~2^-11, joins the W fp16 error).
// Weight fragments: <=64 VGPR in flight at any time so regalloc keeps them.
__global__ __launch_bounds__(1024, 4) void scl_mfma(
    const float* __restrict__ cond, const float* __restrict__ act,
    const float* __restrict__ b1, const float* __restrict__ b2,
    const float* __restrict__ b3,
    const _Float16* __restrict__ wf,
    float* __restrict__ out)
{
    // LDS 33792 B:
    //   [0,16896)      x1 [32][264] f16        (dead after L2)
    //   [16896,33792)  x2 [32][264] f16        (dead after L3 MFMAs)
    //   [0,33792)      h: 32 rows x 1056 B, swizzled (overlays x1+x2)
    __shared__ char smem[33792];
    _Float16* x1 = (_Float16*)smem;
    _Float16* x2 = (_Float16*)(smem + 16896);

    const int tid = threadIdx.x;
    const int w   = tid >> 6;   // wave 0..15
    const int l   = tid & 63;
    const int lr  = l & 15;
    const int lg  = l >> 4;
    const int rb  = blockIdx.x * 32;
    const f16x8* wp = (const f16x8*)wf;   // page stride 64 (f16x8 units)

    // ---- prologue loads: cond (2 m-tiles), W1 (2 pages), W2 (8 pages), biases,
    //      act rows for the tail waves.
    f16x8 a1[2][2];
    #pragma unroll
    for (int m = 0; m < 2; ++m) {
        const float* crow = cond + (rb + m * 16 + lr) * 64 + lg * 8;
        #pragma unroll
        for (int kt = 0; kt < 2; ++kt) {
            f4 va = *(const f4*)(crow + kt * 32);
            f4 vb = *(const f4*)(crow + kt * 32 + 4);
            #pragma unroll
            for (int j = 0; j < 4; ++j) {
                a1[m][kt][j]     = (_Float16)va[j];
                a1[m][kt][4 + j] = (_Float16)vb[j];
            }
        }
    }
    f16x8 w1f[2];
    #pragma unroll
    for (int kt = 0; kt < 2; ++kt) w1f[kt] = wp[(w * 2 + kt) * 64 + l];
    f16x8 w2f[8];
    #pragma unroll
    for (int kt = 0; kt < 8; ++kt) w2f[kt] = wp[2048 + (w * 8 + kt) * 64 + l];
    float b1v = b1[w * 16 + lr];
    float b2v = b2[w * 16 + lr];
    float b3v[2];
    #pragma unroll
    for (int n = 0; n < 2; ++n) b3v[n] = b3[(w * 2 + n) * 16 + lr];

    f4 av0 = {}, av1 = {};
    if (w < 4) {   // tail waves: act row = rb + w*8 + (l>>3), cols (l&7)*8..+8
        const float* ap = act + (rb + w * 8 + (l >> 3)) * 64 + (l & 7) * 8;
        av0 = *(const f4*)ap;
        av1 = *(const f4*)(ap + 4);
    }

    // ---------------- layer 1: cond[32x64] @ W1 -> x1 (fp16, single plane)
    {
        f32x4 acc[2] = {};
        #pragma unroll
        for (int kt = 0; kt < 2; ++kt)
            #pragma unroll
            for (int m = 0; m < 2; ++m)
                acc[m] = __builtin_amdgcn_mfma_f32_16x16x32_f16(a1[m][kt], w1f[kt], acc[m], 0, 0, 0);
        #pragma unroll
        for (int m = 0; m < 2; ++m)
            #pragma unroll
            for (int r = 0; r < 4; ++r) {
                float v = ftanh(acc[m][r] + b1v);   // C/D: col=l&15, row=(l>>4)*4+r
                x1[(m * 16 + lg * 4 + r) * 264 + w * 16 + lr] = (_Float16)v;
            }
    }
    BARLG();

    // ---------------- layer 2 (W3 first half prefetched across this phase)
    f16x8 w3a[2][4];
    #pragma unroll
    for (int n = 0; n < 2; ++n)
        #pragma unroll
        for (int kt = 0; kt < 4; ++kt)
            w3a[n][kt] = wp[10240 + ((w * 2 + n) * 8 + kt) * 64 + l];
    {
        f32x4 acc[2] = {};
        #pragma unroll
        for (int kt = 0; kt < 8; ++kt) {
            int cb = kt * 32 + lg * 8;
            f16x8 am0 = *(const f16x8*)&x1[lr * 264 + cb];
            f16x8 am1 = *(const f16x8*)&x1[(16 + lr) * 264 + cb];
            acc[0] = __builtin_amdgcn_mfma_f32_16x16x32_f16(am0, w2f[kt], acc[0], 0, 0, 0);
            acc[1] = __builtin_amdgcn_mfma_f32_16x16x32_f16(am1, w2f[kt], acc[1], 0, 0, 0);
        }
        #pragma unroll
        for (int m = 0; m < 2; ++m)
            #pragma unroll
            for (int r = 0; r < 4; ++r) {
                float v = ftanh(acc[m][r] + b2v);
                x2[(m * 16 + lg * 4 + r) * 264 + w * 16 + lr] = (_Float16)v;
            }
    }
    BARLG();

    // ---------------- layer 3 (W3 second half prefetched across the MFMA loop)
    f16x8 w3b[2][4];
    #pragma unroll
    for (int n = 0; n < 2; ++n)
        #pragma unroll
        for (int kt = 0; kt < 4; ++kt)
            w3b[n][kt] = wp[10240 + ((w * 2 + n) * 8 + (kt + 4)) * 64 + l];
    f32x4 acc3[2][2] = {};
    #pragma unroll
    for (int kt = 0; kt < 4; ++kt) {
        int cb = kt * 32 + lg * 8;
        f16x8 am0 = *(const f16x8*)&x2[lr * 264 + cb];
        f16x8 am1 = *(const f16x8*)&x2[(16 + lr) * 264 + cb];
        #pragma unroll
        for (int n = 0; n < 2; ++n) {
            acc3[0][n] = __builtin_amdgcn_mfma_f32_16x16x32_f16(am0, w3a[n][kt], acc3[0][n], 0, 0, 0);
            acc3[1][n] = __builtin_amdgcn_mfma_f32_16x16x32_f16(am1, w3a[n][kt], acc3[1][n], 0, 0, 0);
        }
    }
    #pragma unroll
    for (int kt = 4; kt < 8; ++kt) {
        int cb = kt * 32 + lg * 8;
        f16x8 am0 = *(const f16x8*)&x2[lr * 264 + cb];
        f16x8 am1 = *(const f16x8*)&x2[(16 + lr) * 264 + cb];
        #pragma unroll
        for (int n = 0; n < 2; ++n) {
            acc3[0][n] = __builtin_amdgcn_mfma_f32_16x16x32_f16(am0, w3b[n][kt - 4], acc3[0][n], 0, 0, 0);
            acc3[1][n] = __builtin_amdgcn_mfma_f32_16x16x32_f16(am1, w3b[n][kt - 4], acc3[1][n], 0, 0, 0);
        }
    }
    BARLG();   // all x2 reads done block-wide before h overlays x2

    #pragma unroll
    for (int n = 0; n < 2; ++n) {
        int col = (w * 2 + n) * 16 + lr;
        #pragma unroll
        for (int m = 0; m < 2; ++m)
            #pragma unroll
            for (int r = 0; r < 4; ++r) {
                int row = m * 16 + lg * 4 + r;
                *(_Float16*)(smem + row * 1056 + HSWZ16(col * 2)) =
                    (_Float16)(acc3[m][n][r] + b3v[n]);
            }
    }
    BARLG();

    // ---------------- Householder tail: waves 0-3 only; 8 lanes/row, 8 elems/lane.
    // Lane (w, l>>3 = row-in-group, c = l&7) owns columns n = 8c..8c+7.
    // h chunk for column n = bytes [n*16, n*16+16) of the row = h[cc=0..7][n].
    if (w < 4) {
        const int c = l & 7;
        const int hrow = w * 8 + (l >> 3);
        const int grow = rb + hrow;
        f16x8 hv[8];
        #pragma unroll
        for (int j = 0; j < 8; ++j)
            hv[j] = *(const f16x8*)(smem + hrow * 1056 + HSWZ16((c * 8 + j) * 16));
        float h[8][8];   // h[cc][j], j -> column 8c+j
        #pragma unroll
        for (int cc = 0; cc < 8; ++cc)
            #pragma unroll
            for (int j = 0; j < 8; ++j)
                h[cc][j] = (float)hv[j][cc];
        float inv[8];
        #pragma unroll
        for (int cc = 0; cc < 8; ++cc) {
            float s = 0.0f;
            #pragma unroll
            for (int j = 0; j < 8; ++j) s += h[cc][j] * h[cc][j];
            inv[cc] = 2.0f / red8(s);
        }
        float u[8] = {av0[0], av0[1], av0[2], av0[3], av1[0], av1[1], av1[2], av1[3]};
        #pragma unroll
        for (int cc = 7; cc >= 0; --cc) {           // a* = E^T Q0..Q7 a
            float d = 0.0f;
            #pragma unroll
            for (int j = 0; j < 8; ++j) d += h[cc][j] * u[j];
            float t = inv[cc] * red8(d);
            #pragma unroll
            for (int j = 0; j < 8; ++j) u[j] -= t * h[cc][j];
        }
        float wv[8];
        #pragma unroll
        for (int j = 0; j < 8; ++j) wv[j] = (c == 0) ? u[j] : 0.0f;   // E a*
        #pragma unroll
        for (int cc = 0; cc < 8; ++cc) {            // q = Q7..Q0 (E a*)
            float d = 0.0f;
            #pragma unroll
            for (int j = 0; j < 8; ++j) d += h[cc][j] * wv[j];
            float t = inv[cc] * red8(d);
            #pragma unroll
            for (int j = 0; j < 8; ++j) wv[j] -= t * h[cc][j];
        }
        f4 o0 = {wv[0], wv[1], wv[2], wv[3]};
        f4 o1 = {wv[4], wv[5], wv[6], wv[7]};
        float* op = out + grow * 64 + c * 8;
        *(f4*)op = o0;
        *(f4*)(op + 4) = o1;
    }
}

extern "C" void kernel_launch(void* const* d_in, const int* in_sizes, int n_in,
                              void* d_out, int out_size, void* d_ws, size_t ws_size,
                              hipStream_t stream) {
    const float* cond = (const float*)d_in[0];
    const float* act  = (const float*)d_in[1];
    const float* W1   = (const float*)d_in[2];
    const float* b1   = (const float*)d_in[3];
    const float* W2   = (const float*)d_in[4];
    const float* b2   = (const float*)d_in[5];
    const float* W3   = (const float*)d_in[6];
    const float* b3   = (const float*)d_in[7];
    float* outp = (float*)d_out;

    _Float16* wf = (_Float16*)d_ws;   // 425984 bytes
    prep_frags_all<<<dim3(26), dim3(256), 0, stream>>>(W1, W2, W3, wf);
    scl_mfma<<<dim3(256), dim3(1024), 0, stream>>>(cond, act, b1, b2, b3, wf, outp);
}